// Round 6
// baseline (456.198 us; speedup 1.0000x reference)
//
#include <hip/hip_runtime.h>

typedef unsigned short u16;
typedef short bf8 __attribute__((ext_vector_type(8)));   // 8 bf16 = 4 VGPR (MFMA A/B frag)
typedef float f32x4 __attribute__((ext_vector_type(4))); // MFMA C/D frag

#define Bc 8
#define Hc 8
#define Lc 1024
#define Dc 512
#define HDc 64

// ---------- bf16 helpers ----------
__device__ __forceinline__ u16 f2bf(float f) {
    unsigned int x; __builtin_memcpy(&x, &f, 4);
    x = x + 0x7fffu + ((x >> 16) & 1u);  // RNE
    return (u16)(x >> 16);
}
union S8 { bf8 v; u16 s[8]; };

// ---------- rel fp32 -> bf16 ----------
__global__ __launch_bounds__(256) void relcvt(const float* __restrict__ src,
                                              u16* __restrict__ dst) {
    const int idx = blockIdx.x * 256 + threadIdx.x;           // 16384 float4
    const float4 v = *(const float4*)(src + (size_t)idx * 4);
    ushort4 o; o.x = f2bf(v.x); o.y = f2bf(v.y); o.z = f2bf(v.z); o.w = f2bf(v.w);
    *(ushort4*)(dst + (size_t)idx * 4) = o;
}

// ---------- W (KxN fp32) -> WT (NxK bf16), 4 weights ----------
__global__ __launch_bounds__(256) void wtrans(
    const float* __restrict__ w0, const float* __restrict__ w1,
    const float* __restrict__ w2, const float* __restrict__ w3,
    u16* __restrict__ o0, u16* __restrict__ o1,
    u16* __restrict__ o2, u16* __restrict__ o3)
{
    const float* W; u16* O;
    switch (blockIdx.z) {
        case 0: W = w0; O = o0; break;
        case 1: W = w1; O = o1; break;
        case 2: W = w2; O = o2; break;
        default: W = w3; O = o3; break;
    }
    __shared__ float tile[64][65];
    const int t = threadIdx.x;
    const int k0 = blockIdx.x * 64, n0 = blockIdx.y * 64;
#pragma unroll
    for (int s = 0; s < 4; ++s) {
        const int idx = s * 256 + t;
        const int r = idx >> 4, c = (idx & 15) * 4;
        const float4 v = *(const float4*)(W + (size_t)(k0 + r) * Dc + n0 + c);
        tile[r][c] = v.x; tile[r][c + 1] = v.y; tile[r][c + 2] = v.z; tile[r][c + 3] = v.w;
    }
    __syncthreads();
#pragma unroll
    for (int s = 0; s < 2; ++s) {
        const int idx = s * 256 + t;
        const int rn = idx >> 3, ck = (idx & 7) * 8;
        S8 o;
#pragma unroll
        for (int u = 0; u < 8; ++u) o.s[u] = f2bf(tile[ck + u][rn]);
        *(bf8*)(O + (size_t)(n0 + rn) * Dc + k0 + ck) = o.v;
    }
}

// ---------- MFMA GEMM core: Y = A(8192x512) @ WT^T + bias ----------
// 64x64 tile, grid.x 1024 (4 blocks/CU). XCD swizzle: mt = xcd + 8*chunk -> A fetched
// once chip-wide, WT L2-resident. Double-buffered LDS, register prefetch, 1 barrier/iter.
__device__ __forceinline__ void gemm_core(
    const void* __restrict__ A, const u16* __restrict__ WT,
    const float* __restrict__ bias, void* __restrict__ Y,
    int aF32, int mode)
{
    __shared__ u16 As[2][64][72];
    __shared__ u16 Bs[2][64][72];

    const int wgid = blockIdx.x;
    const int xcd = wgid & 7, rr = wgid >> 3;
    const int mt = xcd + 8 * (rr >> 3), ntile = rr & 7;
    const int m0 = mt * 64, n0 = ntile * 64;

    const int t = threadIdx.x;
    const int w = t >> 6, lane = t & 63, quad = lane >> 4, l15 = lane & 15;
    const int ra = t >> 2, ca = (t & 3) * 16;   // staging: row, 16-col block

    f32x4 acc[4] = {};

    // prologue: stage k0 = 0 into buf 0
    {
        S8 o0, o1;
        if (aF32) {
            const float* ap = (const float*)A + (size_t)(m0 + ra) * Dc + ca;
            const float4 v0 = *(const float4*)ap,       v1 = *(const float4*)(ap + 4);
            const float4 v2 = *(const float4*)(ap + 8), v3 = *(const float4*)(ap + 12);
            o0.s[0] = f2bf(v0.x); o0.s[1] = f2bf(v0.y); o0.s[2] = f2bf(v0.z); o0.s[3] = f2bf(v0.w);
            o0.s[4] = f2bf(v1.x); o0.s[5] = f2bf(v1.y); o0.s[6] = f2bf(v1.z); o0.s[7] = f2bf(v1.w);
            o1.s[0] = f2bf(v2.x); o1.s[1] = f2bf(v2.y); o1.s[2] = f2bf(v2.z); o1.s[3] = f2bf(v2.w);
            o1.s[4] = f2bf(v3.x); o1.s[5] = f2bf(v3.y); o1.s[6] = f2bf(v3.z); o1.s[7] = f2bf(v3.w);
        } else {
            const u16* ap = (const u16*)A + (size_t)(m0 + ra) * Dc + ca;
            o0.v = *(const bf8*)ap; o1.v = *(const bf8*)(ap + 8);
        }
        *(bf8*)&As[0][ra][ca] = o0.v; *(bf8*)&As[0][ra][ca + 8] = o1.v;
        const u16* bp = WT + (size_t)(n0 + ra) * Dc + ca;
        *(bf8*)&Bs[0][ra][ca] = *(const bf8*)bp;
        *(bf8*)&Bs[0][ra][ca + 8] = *(const bf8*)(bp + 8);
    }

    int cur = 0;
    for (int k0 = 0; k0 < Dc; k0 += 64) {
        __syncthreads();                 // buf[cur] ready; buf[cur^1] reads drained
        const bool pf = (k0 + 64 < Dc);
        float4 v0, v1, v2, v3; bf8 an0 = {}, an1 = {}, bn0 = {}, bn1 = {};
        if (pf) {                        // issue next-tile loads early
            const int kn = k0 + 64;
            if (aF32) {
                const float* ap = (const float*)A + (size_t)(m0 + ra) * Dc + kn + ca;
                v0 = *(const float4*)ap;       v1 = *(const float4*)(ap + 4);
                v2 = *(const float4*)(ap + 8); v3 = *(const float4*)(ap + 12);
            } else {
                const u16* ap = (const u16*)A + (size_t)(m0 + ra) * Dc + kn + ca;
                an0 = *(const bf8*)ap; an1 = *(const bf8*)(ap + 8);
            }
            const u16* bp = WT + (size_t)(n0 + ra) * Dc + kn + ca;
            bn0 = *(const bf8*)bp; bn1 = *(const bf8*)(bp + 8);
        }

#pragma unroll
        for (int ks = 0; ks < 2; ++ks) {
            const bf8 a = *(const bf8*)&As[cur][w * 16 + l15][ks * 32 + quad * 8];
#pragma unroll
            for (int nt = 0; nt < 4; ++nt) {
                const bf8 b = *(const bf8*)&Bs[cur][nt * 16 + l15][ks * 32 + quad * 8];
                acc[nt] = __builtin_amdgcn_mfma_f32_16x16x32_bf16(a, b, acc[nt], 0, 0, 0);
            }
        }

        if (pf) {                        // convert + ds_write into other buffer
            S8 o0, o1;
            if (aF32) {
                o0.s[0] = f2bf(v0.x); o0.s[1] = f2bf(v0.y); o0.s[2] = f2bf(v0.z); o0.s[3] = f2bf(v0.w);
                o0.s[4] = f2bf(v1.x); o0.s[5] = f2bf(v1.y); o0.s[6] = f2bf(v1.z); o0.s[7] = f2bf(v1.w);
                o1.s[0] = f2bf(v2.x); o1.s[1] = f2bf(v2.y); o1.s[2] = f2bf(v2.z); o1.s[3] = f2bf(v2.w);
                o1.s[4] = f2bf(v3.x); o1.s[5] = f2bf(v3.y); o1.s[6] = f2bf(v3.z); o1.s[7] = f2bf(v3.w);
            } else { o0.v = an0; o1.v = an1; }
            *(bf8*)&As[cur ^ 1][ra][ca] = o0.v; *(bf8*)&As[cur ^ 1][ra][ca + 8] = o1.v;
            *(bf8*)&Bs[cur ^ 1][ra][ca] = bn0;  *(bf8*)&Bs[cur ^ 1][ra][ca + 8] = bn1;
            cur ^= 1;
        }
    }

#pragma unroll
    for (int nt = 0; nt < 4; ++nt) {
        const int n = n0 + nt * 16 + l15;
        const float bv = bias[n];
#pragma unroll
        for (int reg = 0; reg < 4; ++reg) {
            const int m = m0 + w * 16 + quad * 4 + reg;
            const float val = acc[nt][reg] + bv;
            if (mode == 0) {
                __builtin_nontemporal_store(val, (float*)Y + (size_t)m * Dc + n);
            } else {
                const int b = m >> 10, l = m & 1023;
                const int h = n >> 6, hd = n & 63;
                ((u16*)Y)[(((size_t)(b * Hc + h)) * Lc + l) * HDc + hd] = f2bf(val);
            }
        }
    }
}

__global__ __launch_bounds__(256) void gemm_mfma(
    const void* __restrict__ A, const u16* __restrict__ WT,
    const float* __restrict__ bias, void* __restrict__ Y,
    int aF32, int mode)
{
    gemm_core(A, WT, bias, Y, aF32, mode);
}

// fused QKV: one dispatch, blockIdx.y selects the GEMM
__global__ __launch_bounds__(256) void gemm_qkv(
    const float* __restrict__ xq, const float* __restrict__ xk, const float* __restrict__ xv,
    const u16* __restrict__ wq, const u16* __restrict__ wk, const u16* __restrict__ wv,
    const float* __restrict__ bq, const float* __restrict__ bk, const float* __restrict__ bv,
    u16* __restrict__ yq, u16* __restrict__ yk, u16* __restrict__ yv)
{
    const float* A; const u16* W; const float* bb; u16* y;
    switch (blockIdx.y) {
        case 0:  A = xq; W = wq; bb = bq; y = yq; break;
        case 1:  A = xk; W = wk; bb = bk; y = yk; break;
        default: A = xv; W = wv; bb = bv; y = yv; break;
    }
    gemm_core(A, W, bb, y, 1, 1);
}

// ---------- MFMA attention ----------
// grid (64 = bh, 16): it = 15 - by -> LPT (longest blocks dispatch first; short blocks
// backfill). linear%8 = bh%8 keeps same-head blocks on one XCD (q/k/v/rel L2-resident).
// LDS 54272 B -> 3 blocks/CU (12 waves). K, es, vst single-buffered w/ register prefetch:
// pass A = 2 barriers/tile (TOP + A2, staging writes post-A2); pass B = 2 (TOP + B2).
// es = 2-half rolling window [mb0+j0, +127], low half lives in buf (jt&1).
// rel skew WRITE-SIDE: writer knows target col jv = c - 15 + row15 -> rs[64][68] read
// straight at [Rl][J]; in pass B, P(f32) overwrites the score slot in-place (same thread);
// PV MFMA reads P f32 + converts (no bf16 copy). Row sums in registers (wave-private rows).
__global__ __launch_bounds__(256) void attn_mfma(
    const u16* __restrict__ q, const u16* __restrict__ k,
    const u16* __restrict__ v, const u16* __restrict__ rel,
    float* __restrict__ attn, u16* __restrict__ ows)
{
    __shared__ u16 kps[64][72];      // K tile [j][d]
    __shared__ u16 vst[64][72];      // V^T tile [d][j], col-blocks rotated
    __shared__ u16 es[2][64][72];    // rel window: 2 halves of 64 rows
    __shared__ float rs[64][68];     // pre-shifted rel scores; pass B: P f32 in-place

    const int bh = blockIdx.x;
    const int it = 15 - (int)blockIdx.y;        // LPT: longest first
    const int i0 = it * 64;
    const int mb0 = 960 - i0;                   // rel window base at jt=0
    const int t = threadIdx.x;
    const int w = t >> 6, lane = t & 63, quad = lane >> 4, l15 = lane & 15;
    const size_t qb = ((size_t)bh << 10);
    const int sr = t >> 3, scb = (t & 7) * 8;   // staging coords: rows sr / sr+32, col blk scb
    const int rb4 = quad * 4;                   // row-in-16 base (add reg)
    const int Rw = w * 16;                      // wave row base

    // q fragments live in registers for the whole block
    bf8 aq[2];
#pragma unroll
    for (int ks = 0; ks < 2; ++ks)
        aq[ks] = *(const bf8*)(q + (qb + i0 + Rw + l15) * HDc + ks * 32 + quad * 8);

    float lsum[4] = {0.f, 0.f, 0.f, 0.f};       // row sums (rows wave-private)

    // ================= pass A: row sums =================
    {   // prologue: stage jt=0 K + es rows [mb0, mb0+127] -> halves 0,1
        *(bf8*)&kps[sr][scb] = *(const bf8*)(k + (qb + sr) * HDc + scb);
        *(bf8*)&kps[32 + sr][scb] = *(const bf8*)(k + (qb + 32 + sr) * HDc + scb);
#pragma unroll
        for (int s = 0; s < 4; ++s) {
            const int idx = s * 256 + t;
            const int r = idx >> 3, cb = (idx & 7) * 8;
            int row = mb0 + r; row = row > 1023 ? 1023 : row;  // OOB -> masked anyway
            *(bf8*)&es[r >> 6][r & 63][cb] = *(const bf8*)(rel + (size_t)row * HDc + cb);
        }
    }
    for (int jt = 0; jt <= it; ++jt) {
        const int j0 = jt * 64;
        const int lo = jt & 1;                  // buf holding window rows 0..63
        __syncthreads();                        // TOP: staged writes visible
        const bool pf = (jt < it);
        bf8 kn0 = {}, kn1 = {}, en0 = {}, en1 = {};
        if (pf) {                               // register prefetch for jt+1
            kn0 = *(const bf8*)(k + (qb + j0 + 64 + sr) * HDc + scb);
            kn1 = *(const bf8*)(k + (qb + j0 + 96 + sr) * HDc + scb);
            const int rbr = mb0 + j0 + 128;
            int r0 = rbr + sr;      r0 = r0 > 1023 ? 1023 : r0;
            int r1 = rbr + 32 + sr; r1 = r1 > 1023 ? 1023 : r1;
            en0 = *(const bf8*)(rel + (size_t)r0 * HDc + scb);
            en1 = *(const bf8*)(rel + (size_t)r1 * HDc + scb);
        }

        f32x4 aS[4] = {}; f32x4 aR[5] = {};
#pragma unroll
        for (int ks = 0; ks < 2; ++ks) {
            const bf8 a = aq[ks];
#pragma unroll
            for (int nt = 0; nt < 4; ++nt) {
                const bf8 b = *(const bf8*)&kps[nt * 16 + l15][ks * 32 + quad * 8];
                aS[nt] = __builtin_amdgcn_mfma_f32_16x16x32_bf16(a, b, aS[nt], 0, 0, 0);
            }
#pragma unroll
            for (int nt = 0; nt < 5; ++nt) {
                const int rr = 3 - w + nt;      // window row block 0..7
                const bf8 b = *(const bf8*)&es[lo ^ (rr >> 2)][(rr & 3) * 16 + l15][ks * 32 + quad * 8];
                aR[nt] = __builtin_amdgcn_mfma_f32_16x16x32_bf16(a, b, aR[nt], 0, 0, 0);
            }
        }
        // write-side-shifted rel scores: target col jv = c - 15 + row15
#pragma unroll
        for (int nt = 0; nt < 5; ++nt)
#pragma unroll
            for (int reg = 0; reg < 4; ++reg) {
                const int jv = nt * 16 + l15 - 15 + rb4 + reg;
                if ((unsigned)jv < 64u) rs[Rw + rb4 + reg][jv] = aR[nt][reg];
            }
        __syncthreads();                        // A2: all kps/es MFMA reads done
        if (pf) {                               // staging writes (visible at next TOP)
            *(bf8*)&kps[sr][scb] = kn0;
            *(bf8*)&kps[32 + sr][scb] = kn1;
            *(bf8*)&es[lo][sr][scb] = en0;      // overwrite retired low half
            *(bf8*)&es[lo][32 + sr][scb] = en1;
        }

        float psum[4] = {0.f, 0.f, 0.f, 0.f};
#pragma unroll
        for (int nt = 0; nt < 4; ++nt) {
#pragma unroll
            for (int reg = 0; reg < 4; ++reg) {
                const int Rl = Rw + rb4 + reg;
                const int J = nt * 16 + l15;
                const float sc = (aS[nt][reg] + rs[Rl][J]) * 0.125f;
                const bool valid = (j0 + J) <= (i0 + Rl);
                psum[reg] += valid ? __expf(sc) : 0.f;
            }
        }
#pragma unroll
        for (int m = 1; m < 16; m <<= 1)
#pragma unroll
            for (int reg = 0; reg < 4; ++reg) psum[reg] += __shfl_xor(psum[reg], m, 64);
#pragma unroll
        for (int reg = 0; reg < 4; ++reg) lsum[reg] += psum[reg];
    }

    __syncthreads();                            // pass-A reads done before pass-B staging
    float ils[4];
#pragma unroll
    for (int reg = 0; reg < 4; ++reg) ils[reg] = 1.f / lsum[reg];

    f32x4 acc[4] = {};                          // PV accumulator (MFMA C layout)

    // ================= pass B: attn write + PV =================
    {   // prologue: stage jt=0 K + V + es
        *(bf8*)&kps[sr][scb] = *(const bf8*)(k + (qb + sr) * HDc + scb);
        *(bf8*)&kps[32 + sr][scb] = *(const bf8*)(k + (qb + 32 + sr) * HDc + scb);
        S8 v0; v0.v = *(const bf8*)(v + (qb + sr) * HDc + scb);
        S8 v1; v1.v = *(const bf8*)(v + (qb + 32 + sr) * HDc + scb);
        const int cp0 = (sr & 7) + 8 * (((sr >> 3) + (scb >> 3)) & 7);
        const int cp1 = (sr & 7) + 8 * ((4 + (sr >> 3) + (scb >> 3)) & 7);
#pragma unroll
        for (int u = 0; u < 8; ++u) vst[scb + u][cp0] = v0.s[u];
#pragma unroll
        for (int u = 0; u < 8; ++u) vst[scb + u][cp1] = v1.s[u];
#pragma unroll
        for (int s = 0; s < 4; ++s) {
            const int idx = s * 256 + t;
            const int r = idx >> 3, cb = (idx & 7) * 8;
            int row = mb0 + r; row = row > 1023 ? 1023 : row;
            *(bf8*)&es[r >> 6][r & 63][cb] = *(const bf8*)(rel + (size_t)row * HDc + cb);
        }
    }
    for (int jt = 0; jt <= it; ++jt) {
        const int j0 = jt * 64;
        const int lo = jt & 1;
        __syncthreads();                        // TOP: staged writes visible
        const bool pf = (jt < it);
        bf8 kn0 = {}, kn1 = {}, vn0 = {}, vn1 = {}, en0 = {}, en1 = {};
        if (pf) {
            kn0 = *(const bf8*)(k + (qb + j0 + 64 + sr) * HDc + scb);
            kn1 = *(const bf8*)(k + (qb + j0 + 96 + sr) * HDc + scb);
            vn0 = *(const bf8*)(v + (qb + j0 + 64 + sr) * HDc + scb);
            vn1 = *(const bf8*)(v + (qb + j0 + 96 + sr) * HDc + scb);
            const int rbr = mb0 + j0 + 128;
            int r0 = rbr + sr;      r0 = r0 > 1023 ? 1023 : r0;
            int r1 = rbr + 32 + sr; r1 = r1 > 1023 ? 1023 : r1;
            en0 = *(const bf8*)(rel + (size_t)r0 * HDc + scb);
            en1 = *(const bf8*)(rel + (size_t)r1 * HDc + scb);
        }

        f32x4 aS[4] = {}; f32x4 aR[5] = {};
#pragma unroll
        for (int ks = 0; ks < 2; ++ks) {
            const bf8 a = aq[ks];
#pragma unroll
            for (int nt = 0; nt < 4; ++nt) {
                const bf8 b = *(const bf8*)&kps[nt * 16 + l15][ks * 32 + quad * 8];
                aS[nt] = __builtin_amdgcn_mfma_f32_16x16x32_bf16(a, b, aS[nt], 0, 0, 0);
            }
#pragma unroll
            for (int nt = 0; nt < 5; ++nt) {
                const int rr = 3 - w + nt;
                const bf8 b = *(const bf8*)&es[lo ^ (rr >> 2)][(rr & 3) * 16 + l15][ks * 32 + quad * 8];
                aR[nt] = __builtin_amdgcn_mfma_f32_16x16x32_bf16(a, b, aR[nt], 0, 0, 0);
            }
        }
#pragma unroll
        for (int nt = 0; nt < 5; ++nt)
#pragma unroll
            for (int reg = 0; reg < 4; ++reg) {
                const int jv = nt * 16 + l15 - 15 + rb4 + reg;
                if ((unsigned)jv < 64u) rs[Rw + rb4 + reg][jv] = aR[nt][reg];
            }

        // exp: read score, overwrite same slot with normalized P (same thread, in-order DS)
#pragma unroll
        for (int nt = 0; nt < 4; ++nt) {
#pragma unroll
            for (int reg = 0; reg < 4; ++reg) {
                const int Rl = Rw + rb4 + reg;
                const int J = nt * 16 + l15;
                const float sc = (aS[nt][reg] + rs[Rl][J]) * 0.125f;
                const bool valid = (j0 + J) <= (i0 + Rl);
                const float p = valid ? __expf(sc) * ils[reg] : 0.f;
                rs[Rl][J] = p;
            }
        }

        // PV via MFMA: read own-wave P rows as f32, convert, multiply V
#pragma unroll
        for (int ks = 0; ks < 2; ++ks) {
            const f32x4 pa0 = *(const f32x4*)&rs[Rw + l15][ks * 32 + quad * 8];
            const f32x4 pa1 = *(const f32x4*)&rs[Rw + l15][ks * 32 + quad * 8 + 4];
            S8 pk;
#pragma unroll
            for (int u = 0; u < 4; ++u) { pk.s[u] = f2bf(pa0[u]); pk.s[4 + u] = f2bf(pa1[u]); }
#pragma unroll
            for (int nt = 0; nt < 4; ++nt) {
                const int d = nt * 16 + l15;
                const bf8 vb = *(const bf8*)&vst[d][8 * (((ks * 4 + quad) + (d >> 3)) & 7)];
                acc[nt] = __builtin_amdgcn_mfma_f32_16x16x32_bf16(pk.v, vb, acc[nt], 0, 0, 0);
            }
        }

        __syncthreads();                        // B2: all waves' P visible; PV/vst reads done
        // coalesced attn store: lanes 0-15 emit 256B/row, nontemporal (protect L2)
        {
            const int trow = t >> 4, tcol = (t & 15) * 4;
#pragma unroll
            for (int s = 0; s < 4; ++s) {
                const f32x4 p4 = *(const f32x4*)&rs[trow + 16 * s][tcol];
                __builtin_nontemporal_store(p4,
                    (f32x4*)(attn + ((size_t)bh * Lc + i0 + trow + 16 * s) * Lc + j0 + tcol));
            }
        }
        if (pf) {                               // staging writes (visible at next TOP)
            *(bf8*)&kps[sr][scb] = kn0;
            *(bf8*)&kps[32 + sr][scb] = kn1;
            S8 a0; a0.v = vn0; S8 a1; a1.v = vn1;
            const int cp0 = (sr & 7) + 8 * (((sr >> 3) + (scb >> 3)) & 7);
            const int cp1 = (sr & 7) + 8 * ((4 + (sr >> 3) + (scb >> 3)) & 7);
#pragma unroll
            for (int u = 0; u < 8; ++u) vst[scb + u][cp0] = a0.s[u];
#pragma unroll
            for (int u = 0; u < 8; ++u) vst[scb + u][cp1] = a1.s[u];
            *(bf8*)&es[lo][sr][scb] = en0;
            *(bf8*)&es[lo][32 + sr][scb] = en1;
        }
    }

    // epilogue: out (already normalized), MFMA C layout
    const int bb = bh >> 3, hh = bh & 7;
#pragma unroll
    for (int nt = 0; nt < 4; ++nt)
#pragma unroll
        for (int reg = 0; reg < 4; ++reg)
            ows[((size_t)(bb * Lc + i0 + Rw + rb4 + reg)) * Dc + hh * HDc + nt * 16 + l15]
                = f2bf(acc[nt][reg]);

    // zero-fill attn cols beyond the causal tiles (nontemporal)
    const int jend = (it + 1) * 64;
    if (jend + t * 4 < Lc) {
        const f32x4 z = {0.f, 0.f, 0.f, 0.f};
        for (int r = 0; r < 64; ++r)
            __builtin_nontemporal_store(z,
                (f32x4*)(attn + ((size_t)bh * Lc + i0 + r) * Lc + jend + t * 4));
    }
}

// ---------- launch ----------
extern "C" void kernel_launch(void* const* d_in, const int* in_sizes, int n_in,
                              void* d_out, int out_size, void* d_ws, size_t ws_size,
                              hipStream_t stream)
{
    const float* x_q = (const float*)d_in[0];
    const float* x_k = (const float*)d_in[1];
    const float* x_v = (const float*)d_in[2];
    // d_in[3] = mask — causal, folded analytically
    const float* Wq = (const float*)d_in[4];
    const float* bq = (const float*)d_in[5];
    const float* Wk = (const float*)d_in[6];
    const float* bk = (const float*)d_in[7];
    const float* Wv = (const float*)d_in[8];
    const float* bv = (const float*)d_in[9];
    const float* Wo = (const float*)d_in[10];
    const float* bo = (const float*)d_in[11];
    const float* rel = (const float*)d_in[12];

    float* out  = (float*)d_out;
    float* attn = out + (size_t)Bc * Lc * Dc;

    // ws carve (bf16)
    u16* relbf = (u16*)d_ws;                             // 1024*64
    u16* wqT = relbf + (size_t)1024 * 64;                // 512*512 each
    u16* wkT = wqT + (size_t)Dc * Dc;
    u16* wvT = wkT + (size_t)Dc * Dc;
    u16* woT = wvT + (size_t)Dc * Dc;
    u16* qbf = woT + (size_t)Dc * Dc;                    // head-split (B,H,L,HD)
    u16* kbf = qbf + (size_t)Bc * Lc * Dc;
    u16* vbf = kbf + (size_t)Bc * Lc * Dc;
    u16* owsbf = vbf + (size_t)Bc * Lc * Dc;             // (B,L,D) flat

    relcvt<<<64, 256, 0, stream>>>(rel, relbf);
    wtrans<<<dim3(8, 8, 4), 256, 0, stream>>>(Wq, Wk, Wv, Wo, wqT, wkT, wvT, woT);

    gemm_qkv<<<dim3(1024, 3), 256, 0, stream>>>(x_q, x_k, x_v, wqT, wkT, wvT,
                                                bq, bk, bv, qbf, kbf, vbf);

    attn_mfma<<<dim3(64, 16), 256, 0, stream>>>(qbf, kbf, vbf, relbf, attn, owsbf);

    gemm_mfma<<<1024, 256, 0, stream>>>(owsbf, woT, bo, out, 0, 0);
}